// Round 15
// baseline (415.439 us; speedup 1.0000x reference)
//
#include <hip/hip_runtime.h>
#include <cstdint>
#include <cstddef>

#define NR_EMB 4096
#define DD 128
#define NTOT 65536   // 32*2048
#define MARGIN 3e-4f
#define RB 16        // rescore batch size

typedef __attribute__((ext_vector_type(8))) short short8;
typedef __attribute__((ext_vector_type(4))) float f32x4;

// ---------------- workspace layout (bytes) ----------------
#define WS_CNT    0u          // uint[4096]
#define WS_SCAL   16384u      // float[16] : [0]=n_total, [1]=loss accum
#define WS_AMBC   16448u      // int[16]   : [0]=ambCnt, [8]=gather ticket
#define WS_COLN   16512u      // float[4096]
#define WS_IDX    32896u      // int[65536]
#define WS_EMBT   295040u     // float[4096*128]  (pidx partials early, embT late)
#define WS_LPART  2392192u    // float[8192] (unused now)
#define WS_ETH    2424960u    // ushort[4096*128] bf16 hi, swizzled
#define WS_ETL    3473536u    // ushort[4096*128] bf16 lo, swizzled
#define WS_AMBL   4522112u    // int[65536]
#define WS_OFF    4784256u    // int[4096]
#define WS_CUR    4800640u    // int[4096]
#define WS_BKT    4817024u    // int[65536]
#define WS_DWT    5079168u    // float[4096*128]  (pval partials early, dwT late)
// total 7,176,320 bytes

// ---------------- output layout (floats) ----------------
#define OUT_Q      0u
#define OUT_LOSS   8388608u
#define OUT_PERP   8388609u
#define OUT_EMB    8388610u
#define OUT_CLUS   8912898u
#define OUT_DW     8916994u

__device__ __forceinline__ unsigned short f2bf(float f) {
    unsigned u = __float_as_uint(f);
    return (unsigned short)((u + 0x7FFFu + ((u >> 16) & 1u)) >> 16);
}
__device__ __forceinline__ float bf2f(unsigned short h) {
    return __uint_as_float(((unsigned)h) << 16);
}

// ---- prep: transpose E -> bf16 hi/lo (swizzled, coalesced writes) + colnorm
//      + zero counts/ambC/scal. 128 blocks x 128 threads (32 codes/block). ----
__global__ __launch_bounds__(128) void k_prep_e(const float* __restrict__ E,
                                                unsigned short* __restrict__ EtHb,
                                                unsigned short* __restrict__ EtLb,
                                                float* __restrict__ coln,
                                                unsigned int* __restrict__ counts,
                                                int* __restrict__ ambC,
                                                float* __restrict__ scal) {
    __shared__ float Es[128][33];
    const int tid = threadIdx.x;          // 0..127
    const int k0  = blockIdx.x * 32;
    if (tid < 32) counts[k0 + tid] = 0u;
    if (blockIdx.x == 0 && tid < 16) ambC[tid] = 0;
    if (blockIdx.x == 1 && tid < 16) scal[tid] = 0.f;
    #pragma unroll
    for (int i = 0; i < 32; ++i) {
        int e = i * 128 + tid;            // 0..4095
        int d = e >> 5, kc = e & 31;
        Es[d][kc] = E[(size_t)d * NR_EMB + k0 + kc];
    }
    __syncthreads();
    const int kc = tid >> 2, q = tid & 3;
    const int k = k0 + kc;
    const int sw = (k & 7) << 3;
    // colnorm: EXACT same source-order fmaf chain as prior rounds (q in [0,4) x 32)
    float cs = 0.f;
    #pragma unroll
    for (int i = 0; i < 32; ++i) {
        float v = Es[q * 32 + i][kc];
        cs = fmaf(v, v, cs);
    }
    // coalesced swizzled output: thread owns OUTPUT chunk [q*32, q*32+32)
    #pragma unroll
    for (int j = 0; j < 4; ++j) {
        short8 hv, lv;
        #pragma unroll
        for (int e = 0; e < 8; ++e) {
            int od = q * 32 + j * 8 + e;
            float v = Es[od ^ sw][kc];
            unsigned short h = f2bf(v);
            hv[e] = (short)h;
            lv[e] = (short)f2bf(v - bf2f(h));
        }
        *(short8*)&EtHb[(size_t)k * DD + q * 32 + j * 8] = hv;
        *(short8*)&EtLb[(size_t)k * DD + q * 32 + j * 8] = lv;
    }
    cs += __shfl_xor(cs, 1);
    cs += __shfl_xor(cs, 2);
    if (q == 0) coln[k] = cs;
}

__device__ __forceinline__ void mrg(float& b1, int& i1, float& b2,
                                    float ob1, int oi1, float ob2) {
    bool take = (ob1 < b1) || (ob1 == b1 && oi1 < i1);
    float loser = take ? b1 : ob1;
    b2 = fminf(fminf(b2, ob2), loser);
    if (take) { b1 = ob1; i1 = oi1; }
}

// ---- main distance/argmin kernel: 3-term bf16-split MFMA, 128 samples/block ----
__global__ __launch_bounds__(256, 2) void k_dist(const float* __restrict__ x,
                                                 const unsigned short* __restrict__ EtHb,
                                                 const unsigned short* __restrict__ EtLb,
                                                 const float* __restrict__ coln,
                                                 int* __restrict__ idx_out,
                                                 unsigned int* __restrict__ counts,
                                                 int* __restrict__ ambCnt,
                                                 int* __restrict__ ambList) {
    __shared__ char lds[65536];   // [buf][EtH 16K | EtL 16K] x2

    const int tid  = threadIdx.x;
    const int lane = tid & 63;
    const int w    = tid >> 6;
    const int n0   = blockIdx.x * 128;
    const int rowbase = (w >> 1) * 32;   // code-half within tile
    const int shalf   = (w & 1) * 64;    // sample-half

    auto stage = [&](int kt, int b) {
        const char* gH = (const char*)EtHb + (size_t)kt * 16384;
        const char* gL = (const char*)EtLb + (size_t)kt * 16384;
        char* lH = lds + b * 32768;
        char* lL = lH + 16384;
        int off = tid * 16;
        #pragma unroll
        for (int j = 0; j < 4; ++j) {
            __builtin_amdgcn_global_load_lds(
                (const __attribute__((address_space(1))) unsigned int*)(gH + off + j * 4096),
                (__attribute__((address_space(3))) unsigned int*)(lH + off + j * 4096), 16, 0, 0);
            __builtin_amdgcn_global_load_lds(
                (const __attribute__((address_space(1))) unsigned int*)(gL + off + j * 4096),
                (__attribute__((address_space(3))) unsigned int*)(lL + off + j * 4096), 16, 0, 0);
        }
    };

    stage(0, 0);

    // ---- A fragments (x hi/lo) in registers for the whole K sweep: 4 m-groups ----
    short8 ah[4][4], al[4][4];
    #pragma unroll
    for (int m = 0; m < 4; ++m) {
        int samp = n0 + shalf + m * 16 + (lane & 15);
        const float* xp = x + (size_t)samp * DD + ((lane >> 4) * 8);
        #pragma unroll
        for (int t = 0; t < 4; ++t) {
            float4 f0 = *(const float4*)(xp + t * 32);
            float4 f1 = *(const float4*)(xp + t * 32 + 4);
            float fv[8] = {f0.x, f0.y, f0.z, f0.w, f1.x, f1.y, f1.z, f1.w};
            short8 h, l;
            #pragma unroll
            for (int j = 0; j < 8; ++j) {
                unsigned short hh = f2bf(fv[j]);
                h[j] = (short)hh;
                l[j] = (short)f2bf(fv[j] - bf2f(hh));
            }
            ah[m][t] = h;
            al[m][t] = l;
        }
    }
    __syncthreads();

    float b1[4][4], b2[4][4];
    int   kb[4][4];
    #pragma unroll
    for (int m = 0; m < 4; ++m)
        #pragma unroll
        for (int r = 0; r < 4; ++r) { b1[m][r] = 3.4e38f; b2[m][r] = 3.4e38f; kb[m][r] = 0; }

    int buf = 0;
    for (int kt = 0; kt < 64; ++kt) {
        if (kt < 63) stage(kt + 1, buf ^ 1);
        const char* lH = lds + buf * 32768;
        const char* lL = lH + 16384;

        #pragma unroll
        for (int n = 0; n < 2; ++n) {
            int row = rowbase + n * 16 + (lane & 15);
            size_t rbo = (size_t)row << 8;
            unsigned swz = (unsigned)((row & 7) << 4);
            float cn = coln[kt * 64 + row];
            int enc = kt * 2 + n;

            f32x4 acc[4];
            #pragma unroll
            for (int m = 0; m < 4; ++m) acc[m] = (f32x4){0.f, 0.f, 0.f, 0.f};

            __builtin_amdgcn_s_setprio(1);
            #pragma unroll
            for (int t = 0; t < 4; ++t) {
                unsigned coff = ((unsigned)(t * 64 + ((lane >> 4) << 4))) ^ swz;
                short8 bh = *(const short8*)(lH + rbo + coff);
                short8 bl = *(const short8*)(lL + rbo + coff);
                #pragma unroll
                for (int m = 0; m < 4; ++m)
                    acc[m] = __builtin_amdgcn_mfma_f32_16x16x32_bf16(ah[m][t], bh, acc[m], 0, 0, 0);
                #pragma unroll
                for (int m = 0; m < 4; ++m)
                    acc[m] = __builtin_amdgcn_mfma_f32_16x16x32_bf16(al[m][t], bh, acc[m], 0, 0, 0);
                #pragma unroll
                for (int m = 0; m < 4; ++m)
                    acc[m] = __builtin_amdgcn_mfma_f32_16x16x32_bf16(ah[m][t], bl, acc[m], 0, 0, 0);
            }
            __builtin_amdgcn_s_setprio(0);

            #pragma unroll
            for (int m = 0; m < 4; ++m) {
                #pragma unroll
                for (int r = 0; r < 4; ++r) {
                    float d = fmaf(-2.f, acc[m][r], cn);
                    bool lt = d < b1[m][r];
                    b2[m][r] = __builtin_amdgcn_fmed3f(d, b1[m][r], b2[m][r]);
                    b1[m][r] = fminf(b1[m][r], d);
                    kb[m][r] = lt ? enc : kb[m][r];
                }
            }
        }
        __syncthreads();
        buf ^= 1;
    }

    // ---- reduce: cross-lane (16 codes/lane-group), then cross-wave code halves ----
    float* sb1 = (float*)lds;
    int*   si1 = (int*)(lds + 1024);
    float* sb2 = (float*)(lds + 2048);

    #pragma unroll
    for (int m = 0; m < 4; ++m) {
        #pragma unroll
        for (int r = 0; r < 4; ++r) {
            float B1 = b1[m][r];
            int   I1 = (kb[m][r] >> 1) * 64 + rowbase + (kb[m][r] & 1) * 16 + (lane & 15);
            float B2 = b2[m][r];
            #pragma unroll
            for (int msk = 1; msk < 16; msk <<= 1) {
                float ob1 = __shfl_xor(B1, msk);
                int   oi1 = __shfl_xor(I1, msk);
                float ob2 = __shfl_xor(B2, msk);
                mrg(B1, I1, B2, ob1, oi1, ob2);
            }
            if ((lane & 15) == 0) {
                int sl = shalf + m * 16 + ((lane >> 4) << 2) + r;   // 0..127
                int ch = w >> 1;
                sb1[ch * 128 + sl] = B1;
                si1[ch * 128 + sl] = I1;
                sb2[ch * 128 + sl] = B2;
            }
        }
    }
    __syncthreads();
    if (tid < 128) {
        float B1 = sb1[tid]; int I1 = si1[tid]; float B2 = sb2[tid];
        mrg(B1, I1, B2, sb1[128 + tid], si1[128 + tid], sb2[128 + tid]);
        idx_out[n0 + tid] = I1;
        atomicAdd(&counts[I1], 1u);   // provisional count (rescore fixes deltas)
        if (B2 - B1 < MARGIN) {
            int p = atomicAdd(ambCnt, 1);
            ambList[p] = n0 + tid;
        }
    }
}

// ---- exact fp32 rescore, k-CHUNKED: each block = (batch of 16 samples) x
//      (chunk of 512 codes). Per-code fmaf order identical to full-scan. ----
__global__ __launch_bounds__(256) void k_rescore(const float* __restrict__ x,
                                                 const float* __restrict__ E,
                                                 const float* __restrict__ coln,
                                                 const int* __restrict__ ambCnt,
                                                 const int* __restrict__ ambList,
                                                 float* __restrict__ pval,
                                                 int* __restrict__ pidx) {
    __shared__ float xs[RB][DD];
    __shared__ float xn[RB];
    __shared__ float rb1[RB][256];
    __shared__ int   ri1[RB][256];

    const int tid = threadIdx.x;
    const int cnt = *ambCnt;
    const int nbatch = (cnt + RB - 1) / RB;
    const int nwork = nbatch * 8;

    for (int wk = blockIdx.x; wk < nwork; wk += gridDim.x) {
        const int b  = wk >> 3;
        const int ch = wk & 7;
        const int e0 = b * RB;
        const int nb = min(RB, cnt - e0);
        __syncthreads();
        #pragma unroll
        for (int p = 0; p < 2; ++p) {
            int slot = p * 256 + tid;
            int e = slot >> 5, c = slot & 31;
            if (e < nb) {
                int s = ambList[e0 + e];
                *(float4*)&xs[e][c * 4] = *(const float4*)&x[(size_t)s * DD + c * 4];
            } else {
                float4 z; z.x = z.y = z.z = z.w = 0.f;
                *(float4*)&xs[e][c * 4] = z;
            }
        }
        __syncthreads();
        if (tid < RB) {
            float a = 0.f;
            for (int d = 0; d < DD; ++d) a = fmaf(xs[tid][d], xs[tid][d], a);
            xn[tid] = a;
        }
        __syncthreads();

        const int ka  = ch * 512 + tid;      // chunk codes [ch*512, ch*512+512)
        const int kb2 = ka + 256;
        const float* Ea = E + ka;
        const float* Eb = E + kb2;
        float acca[RB], accb[RB];
        #pragma unroll
        for (int e = 0; e < RB; ++e) { acca[e] = 0.f; accb[e] = 0.f; }

        float4 cA, cB, nA, nB;
        {
            cA.x = Ea[0];                  cA.y = Ea[(size_t)1 * NR_EMB];
            cA.z = Ea[(size_t)2 * NR_EMB]; cA.w = Ea[(size_t)3 * NR_EMB];
            cB.x = Eb[0];                  cB.y = Eb[(size_t)1 * NR_EMB];
            cB.z = Eb[(size_t)2 * NR_EMB]; cB.w = Eb[(size_t)3 * NR_EMB];
            const size_t d1 = (size_t)4 * NR_EMB;
            nA.x = Ea[d1];                nA.y = Ea[d1 + NR_EMB];
            nA.z = Ea[d1 + 2 * NR_EMB];   nA.w = Ea[d1 + 3 * NR_EMB];
            nB.x = Eb[d1];                nB.y = Eb[d1 + NR_EMB];
            nB.z = Eb[d1 + 2 * NR_EMB];   nB.w = Eb[d1 + 3 * NR_EMB];
        }

        for (int d4 = 0; d4 < 30; ++d4) {
            float4 fA, fB;
            const size_t dn = (size_t)(d4 * 4 + 8) * NR_EMB;
            fA.x = Ea[dn];                fA.y = Ea[dn + NR_EMB];
            fA.z = Ea[dn + 2 * NR_EMB];   fA.w = Ea[dn + 3 * NR_EMB];
            fB.x = Eb[dn];                fB.y = Eb[dn + NR_EMB];
            fB.z = Eb[dn + 2 * NR_EMB];   fB.w = Eb[dn + 3 * NR_EMB];
            #pragma unroll
            for (int e = 0; e < RB; ++e) {
                float4 xv = *(const float4*)&xs[e][d4 * 4];
                acca[e] = fmaf(xv.x, cA.x, acca[e]);
                acca[e] = fmaf(xv.y, cA.y, acca[e]);
                acca[e] = fmaf(xv.z, cA.z, acca[e]);
                acca[e] = fmaf(xv.w, cA.w, acca[e]);
                accb[e] = fmaf(xv.x, cB.x, accb[e]);
                accb[e] = fmaf(xv.y, cB.y, accb[e]);
                accb[e] = fmaf(xv.z, cB.z, accb[e]);
                accb[e] = fmaf(xv.w, cB.w, accb[e]);
            }
            cA = nA; cB = nB; nA = fA; nB = fB;
        }
        #pragma unroll
        for (int e = 0; e < RB; ++e) {   // d4 = 30 (in cA/cB)
            float4 xv = *(const float4*)&xs[e][120];
            acca[e] = fmaf(xv.x, cA.x, acca[e]);
            acca[e] = fmaf(xv.y, cA.y, acca[e]);
            acca[e] = fmaf(xv.z, cA.z, acca[e]);
            acca[e] = fmaf(xv.w, cA.w, acca[e]);
            accb[e] = fmaf(xv.x, cB.x, accb[e]);
            accb[e] = fmaf(xv.y, cB.y, accb[e]);
            accb[e] = fmaf(xv.z, cB.z, accb[e]);
            accb[e] = fmaf(xv.w, cB.w, accb[e]);
        }
        #pragma unroll
        for (int e = 0; e < RB; ++e) {   // d4 = 31 (in nA/nB)
            float4 xv = *(const float4*)&xs[e][124];
            acca[e] = fmaf(xv.x, nA.x, acca[e]);
            acca[e] = fmaf(xv.y, nA.y, acca[e]);
            acca[e] = fmaf(xv.z, nA.z, acca[e]);
            acca[e] = fmaf(xv.w, nA.w, acca[e]);
            accb[e] = fmaf(xv.x, nB.x, accb[e]);
            accb[e] = fmaf(xv.y, nB.y, accb[e]);
            accb[e] = fmaf(xv.z, nB.z, accb[e]);
            accb[e] = fmaf(xv.w, nB.w, accb[e]);
        }

        const float cna = coln[ka];
        const float cnb = coln[kb2];
        float b1[RB]; int i1[RB];
        #pragma unroll
        for (int e = 0; e < RB; ++e) {
            float da = (xn[e] - 2.0f * acca[e]) + cna;   // numpy association order
            float db = (xn[e] - 2.0f * accb[e]) + cnb;
            bool ltb = db < da;                          // ka < kb2: strict <
            b1[e] = ltb ? db : da;
            i1[e] = ltb ? kb2 : ka;
        }

        #pragma unroll
        for (int e = 0; e < RB; ++e) { rb1[e][tid] = b1[e]; ri1[e][tid] = i1[e]; }
        __syncthreads();
        {
            int g = tid >> 4, l = tid & 15;
            float B = rb1[g][l]; int I = ri1[g][l];
            #pragma unroll
            for (int j = 1; j < 16; ++j) {
                float ob = rb1[g][l + 16 * j]; int oi = ri1[g][l + 16 * j];
                if (ob < B || (ob == B && oi < I)) { B = ob; I = oi; }
            }
            #pragma unroll
            for (int m = 1; m < 16; m <<= 1) {
                float ob = __shfl_xor(B, m, 16);
                int   oi = __shfl_xor(I, m, 16);
                if (ob < B || (ob == B && oi < I)) { B = ob; I = oi; }
            }
            if (l == 0 && g < nb) {
                pval[wk * RB + g] = B;
                pidx[wk * RB + g] = I;
            }
        }
    }
}

// ---- fused: rescore-merge (rfinal) + stats + exclusive prefix. 1 block. ----
__global__ __launch_bounds__(256) void k_rstats(const int* __restrict__ ambCnt,
                                                const int* __restrict__ ambList,
                                                const float* __restrict__ pval,
                                                const int* __restrict__ pidx,
                                                int* __restrict__ idx_out,
                                                unsigned int* __restrict__ counts,
                                                const float* __restrict__ emaC,
                                                float* __restrict__ outC,
                                                float* __restrict__ scal,
                                                float* __restrict__ outPerp,
                                                int* __restrict__ off,
                                                int* __restrict__ cursor) {
    const int tid = threadIdx.x;
    // ---- phase 1: merge 8 chunk-partials per ambiguous sample ----
    const int cnt = *ambCnt;
    for (int i = tid; i < cnt; i += 256) {
        int b = i >> 4, g = i & 15;
        float B = pval[(b * 8) * RB + g];
        int   I = pidx[(b * 8) * RB + g];
        #pragma unroll
        for (int ch = 1; ch < 8; ++ch) {
            float ob = pval[(b * 8 + ch) * RB + g];
            int   oi = pidx[(b * 8 + ch) * RB + g];
            if (ob < B || (ob == B && oi < I)) { B = ob; I = oi; }
        }
        int s = ambList[i];
        int old = idx_out[s];
        if (I != old) {
            atomicSub(&counts[old], 1u);
            atomicAdd(&counts[I], 1u);
            idx_out[s] = I;
        }
    }
    __threadfence();
    __syncthreads();

    // ---- phase 2: stats + prefix (identical arithmetic to prior rounds) ----
    __shared__ float rs[256], rp[256];
    __shared__ int rc[256];
    float sc = 0.f, sp = 0.f;
    int csum = 0;
    int lc[16];
    #pragma unroll
    for (int j = 0; j < 16; ++j) {
        int k = tid * 16 + j;
        int c = (int)counts[k];
        lc[j] = csum; csum += c;
        float nc = emaC[k] * 0.99f + (float)c * 0.01f;
        outC[k] = nc;
        sc += nc;
        float p = (float)c * (1.0f / 65536.0f);
        sp += p * logf(p + 1e-10f);
    }
    rs[tid] = sc; rp[tid] = sp; rc[tid] = csum;
    __syncthreads();
    for (int o = 1; o < 256; o <<= 1) {
        int v = (tid >= o) ? rc[tid - o] : 0;
        __syncthreads();
        rc[tid] += v;
        __syncthreads();
    }
    const int base = rc[tid] - csum;
    #pragma unroll
    for (int j = 0; j < 16; ++j) {
        int k = tid * 16 + j;
        int o = base + lc[j];
        off[k] = o;
        cursor[k] = o;
    }
    for (int o = 128; o > 0; o >>= 1) {
        if (tid < o) { rs[tid] += rs[tid + o]; rp[tid] += rp[tid + o]; }
        __syncthreads();
    }
    if (tid == 0) {
        scal[0] = rs[0];
        outPerp[0] = expf(-rp[0]);
    }
}

// ---- CSR build: fill buckets ----
__global__ __launch_bounds__(256) void k_fill(const int* __restrict__ idx,
                                              int* __restrict__ cursor,
                                              int* __restrict__ bucket) {
    for (int i = blockIdx.x * 256 + threadIdx.x; i < NTOT; i += gridDim.x * 256) {
        int k = idx[i];
        int p = atomicAdd(&cursor[k], 1);
        bucket[p] = i;
    }
}

// ---- per-code dw sum (atomic-free, coalesced, 2-ahead bucket prefetch) ----
__global__ __launch_bounds__(128) void k_dw(const float* __restrict__ x,
                                            const int* __restrict__ off,
                                            const unsigned int* __restrict__ counts,
                                            const int* __restrict__ bucket,
                                            float* __restrict__ dwT) {
    const int k = blockIdx.x;
    const int d = threadIdx.x;
    const int o = off[k];
    const int c = (int)counts[k];
    float acc = 0.f;
    if (c > 0) {
        int s0 = bucket[o];
        int s1 = (c > 1) ? bucket[o + 1] : 0;
        int p = 0;
        for (; p < c - 2; ++p) {
            int s2 = bucket[o + p + 2];
            acc += x[(size_t)s0 * DD + d];
            s0 = s1; s1 = s2;
        }
        acc += x[(size_t)s0 * DD + d];
        if (c > 1) acc += x[(size_t)s1 * DD + d];
    }
    dwT[(size_t)k * DD + d] = acc;
}

__global__ __launch_bounds__(256) void k_emb(const float* __restrict__ emaDw,
                                             const float* __restrict__ emaC,
                                             const unsigned int* __restrict__ counts,
                                             const float* __restrict__ dwT,
                                             const float* __restrict__ scal,
                                             float* __restrict__ outDw,
                                             float* __restrict__ outEmb,
                                             float* __restrict__ embT) {
    int g = blockIdx.x * 256 + threadIdx.x;
    int d = g >> 12;
    int k = g & 4095;
    float dw  = emaDw[g] * 0.99f + dwT[k * DD + d] * 0.01f;
    float cnt = (float)counts[k];
    float nc  = emaC[k] * 0.99f + cnt * 0.01f;
    float n   = scal[0];
    float denom = n * (nc + 1e-5f) / (n + 0.04096f);
    float e = dw / denom;
    outDw[g]  = dw;
    outEmb[g] = e;
    embT[k * DD + d] = e;
}

// ---- gather + straight-through + fused loss (atomic + last-block write) ----
__global__ __launch_bounds__(256) void k_gather(const float* __restrict__ x,
                                                const float* __restrict__ embT,
                                                const int* __restrict__ idx,
                                                float* __restrict__ q,
                                                float* __restrict__ lossAcc,
                                                int* __restrict__ ticket,
                                                float* __restrict__ outLoss) {
    __shared__ float wred[4];
    int g = blockIdx.x * 256 + threadIdx.x;
    int n = g >> 4;
    int c = g & 15;
    int k = idx[n];
    const float* ep = &embT[(size_t)k * DD + c * 8];
    const float* xp = &x[(size_t)n * DD + c * 8];
    float4 e0 = *(const float4*)(ep);
    float4 e1 = *(const float4*)(ep + 4);
    float4 x0 = *(const float4*)(xp);
    float4 x1 = *(const float4*)(xp + 4);
    float s = 0.f;
    float4 q0, q1;
    {
        float dx = e0.x - x0.x, dy = e0.y - x0.y, dz = e0.z - x0.z, dw = e0.w - x0.w;
        q0.x = x0.x + dx; q0.y = x0.y + dy; q0.z = x0.z + dz; q0.w = x0.w + dw;
        s += dx * dx + dy * dy + dz * dz + dw * dw;
    }
    {
        float dx = e1.x - x1.x, dy = e1.y - x1.y, dz = e1.z - x1.z, dw = e1.w - x1.w;
        q1.x = x1.x + dx; q1.y = x1.y + dy; q1.z = x1.z + dz; q1.w = x1.w + dw;
        s += dx * dx + dy * dy + dz * dz + dw * dw;
    }
    float* qp = &q[(size_t)n * DD + c * 8];
    *(float4*)(qp)     = q0;
    *(float4*)(qp + 4) = q1;
    #pragma unroll
    for (int off = 32; off > 0; off >>= 1) s += __shfl_down(s, off);
    if ((threadIdx.x & 63) == 0) wred[threadIdx.x >> 6] = s;
    __syncthreads();
    if (threadIdx.x == 0) {
        float bs = wred[0] + wred[1] + wred[2] + wred[3];
        atomicAdd(lossAcc, bs);
        __threadfence();
        int old = atomicAdd(ticket, 1);
        if (old == (int)gridDim.x - 1) {
            float tot = atomicAdd(lossAcc, 0.0f);   // fetch final total
            outLoss[0] = tot * (1.0f / 8388608.0f);
        }
    }
}

extern "C" void kernel_launch(void* const* d_in, const int* in_sizes, int n_in,
                              void* d_out, int out_size, void* d_ws, size_t ws_size,
                              hipStream_t stream) {
    const float* x     = (const float*)d_in[0];
    const float* E     = (const float*)d_in[1];
    const float* emaC  = (const float*)d_in[2];
    const float* emaDw = (const float*)d_in[3];
    float* out = (float*)d_out;
    char*  ws  = (char*)d_ws;

    unsigned int*   cnts  = (unsigned int*)(ws + WS_CNT);
    float*          scal  = (float*)(ws + WS_SCAL);
    int*            ambC  = (int*)(ws + WS_AMBC);
    float*          coln  = (float*)(ws + WS_COLN);
    int*            idx   = (int*)(ws + WS_IDX);
    float*          embT  = (float*)(ws + WS_EMBT);   // pidx partials early / embT late
    unsigned short* EtHb  = (unsigned short*)(ws + WS_ETH);
    unsigned short* EtLb  = (unsigned short*)(ws + WS_ETL);
    int*            ambL  = (int*)(ws + WS_AMBL);
    int*            off   = (int*)(ws + WS_OFF);
    int*            cur   = (int*)(ws + WS_CUR);
    int*            bkt   = (int*)(ws + WS_BKT);
    float*          dwT   = (float*)(ws + WS_DWT);    // pval partials early / dwT late

    float* pval = dwT;            // aliased: dwT written later by k_dw
    int*   pidx = (int*)embT;     // aliased: embT written later by k_emb

    k_prep_e<<<128, 128, 0, stream>>>(E, EtHb, EtLb, coln, cnts, ambC, scal);
    k_dist<<<NTOT / 128, 256, 0, stream>>>(x, EtHb, EtLb, coln, idx, cnts, ambC, ambL);
    k_rescore<<<2048, 256, 0, stream>>>(x, E, coln, ambC, ambL, pval, pidx);
    k_rstats<<<1, 256, 0, stream>>>(ambC, ambL, pval, pidx, idx, cnts,
                                    emaC, out + OUT_CLUS, scal, out + OUT_PERP, off, cur);
    k_fill<<<256, 256, 0, stream>>>(idx, cur, bkt);
    k_dw<<<NR_EMB, 128, 0, stream>>>(x, off, cnts, bkt, dwT);
    k_emb<<<(DD * NR_EMB) / 256, 256, 0, stream>>>(emaDw, emaC, cnts, dwT, scal,
                                                   out + OUT_DW, out + OUT_EMB, embT);
    k_gather<<<(NTOT * DD / 8) / 256, 256, 0, stream>>>(x, embT, idx, out + OUT_Q,
                                                        scal + 1, ambC + 8,
                                                        out + OUT_LOSS);
}

// Round 16
// 262.911 us; speedup vs baseline: 1.5802x; 1.5802x over previous
//
#include <hip/hip_runtime.h>
#include <cstdint>
#include <cstddef>

#define NR_EMB 4096
#define DD 128
#define NTOT 65536   // 32*2048
#define MARGIN 3e-4f
#define RB 16        // rescore batch size

typedef __attribute__((ext_vector_type(8))) short short8;
typedef __attribute__((ext_vector_type(4))) float f32x4;

// ---------------- workspace layout (bytes) ----------------
#define WS_CNT    0u          // uint[4096]
#define WS_SCAL   16384u      // float[16] : [0]=n_total
#define WS_AMBC   16448u      // int[16]   : [0]=ambCnt
#define WS_COLN   16512u      // float[4096]
#define WS_IDX    32896u      // int[65536]
#define WS_EMBT   295040u     // float[4096*128]  (pidx partials early, embT late)
#define WS_LPART  2392192u    // float[8192]
#define WS_ETH    2424960u    // ushort[4096*128] bf16 hi, swizzled
#define WS_ETL    3473536u    // ushort[4096*128] bf16 lo, swizzled
#define WS_AMBL   4522112u    // int[65536]
#define WS_OFF    4784256u    // int[4096]
#define WS_CUR    4800640u    // int[4096]
#define WS_BKT    4817024u    // int[65536]
#define WS_DWT    5079168u    // float[4096*128]  (pval partials early, dwT late)
// total 7,176,320 bytes

// ---------------- output layout (floats) ----------------
#define OUT_Q      0u
#define OUT_LOSS   8388608u
#define OUT_PERP   8388609u
#define OUT_EMB    8388610u
#define OUT_CLUS   8912898u
#define OUT_DW     8916994u

__device__ __forceinline__ unsigned short f2bf(float f) {
    unsigned u = __float_as_uint(f);
    return (unsigned short)((u + 0x7FFFu + ((u >> 16) & 1u)) >> 16);
}
__device__ __forceinline__ float bf2f(unsigned short h) {
    return __uint_as_float(((unsigned)h) << 16);
}

// ---- prep: transpose E -> bf16 hi/lo (swizzled, coalesced writes) + colnorm
//      + zero counts/ambC/scal. 128 blocks x 128 threads (32 codes/block). ----
__global__ __launch_bounds__(128) void k_prep_e(const float* __restrict__ E,
                                                unsigned short* __restrict__ EtHb,
                                                unsigned short* __restrict__ EtLb,
                                                float* __restrict__ coln,
                                                unsigned int* __restrict__ counts,
                                                int* __restrict__ ambC,
                                                float* __restrict__ scal) {
    __shared__ float Es[128][33];
    const int tid = threadIdx.x;          // 0..127
    const int k0  = blockIdx.x * 32;
    if (tid < 32) counts[k0 + tid] = 0u;
    if (blockIdx.x == 0 && tid < 16) ambC[tid] = 0;
    if (blockIdx.x == 1 && tid < 16) scal[tid] = 0.f;
    #pragma unroll
    for (int i = 0; i < 32; ++i) {
        int e = i * 128 + tid;            // 0..4095
        int d = e >> 5, kc = e & 31;
        Es[d][kc] = E[(size_t)d * NR_EMB + k0 + kc];
    }
    __syncthreads();
    const int kc = tid >> 2, q = tid & 3;
    const int k = k0 + kc;
    const int sw = (k & 7) << 3;
    // colnorm: EXACT same source-order fmaf chain as prior rounds (q in [0,4) x 32)
    float cs = 0.f;
    #pragma unroll
    for (int i = 0; i < 32; ++i) {
        float v = Es[q * 32 + i][kc];
        cs = fmaf(v, v, cs);
    }
    // coalesced swizzled output: thread owns OUTPUT chunk [q*32, q*32+32)
    #pragma unroll
    for (int j = 0; j < 4; ++j) {
        short8 hv, lv;
        #pragma unroll
        for (int e = 0; e < 8; ++e) {
            int od = q * 32 + j * 8 + e;
            float v = Es[od ^ sw][kc];
            unsigned short h = f2bf(v);
            hv[e] = (short)h;
            lv[e] = (short)f2bf(v - bf2f(h));
        }
        *(short8*)&EtHb[(size_t)k * DD + q * 32 + j * 8] = hv;
        *(short8*)&EtLb[(size_t)k * DD + q * 32 + j * 8] = lv;
    }
    cs += __shfl_xor(cs, 1);
    cs += __shfl_xor(cs, 2);
    if (q == 0) coln[k] = cs;
}

__device__ __forceinline__ void mrg(float& b1, int& i1, float& b2,
                                    float ob1, int oi1, float ob2) {
    bool take = (ob1 < b1) || (ob1 == b1 && oi1 < i1);
    float loser = take ? b1 : ob1;
    b2 = fminf(fminf(b2, ob2), loser);
    if (take) { b1 = ob1; i1 = oi1; }
}

// ---- main distance/argmin kernel: 3-term bf16-split MFMA, 128 samples/block ----
__global__ __launch_bounds__(256, 2) void k_dist(const float* __restrict__ x,
                                                 const unsigned short* __restrict__ EtHb,
                                                 const unsigned short* __restrict__ EtLb,
                                                 const float* __restrict__ coln,
                                                 int* __restrict__ idx_out,
                                                 unsigned int* __restrict__ counts,
                                                 int* __restrict__ ambCnt,
                                                 int* __restrict__ ambList) {
    __shared__ char lds[65536];   // [buf][EtH 16K | EtL 16K] x2

    const int tid  = threadIdx.x;
    const int lane = tid & 63;
    const int w    = tid >> 6;
    const int n0   = blockIdx.x * 128;
    const int rowbase = (w >> 1) * 32;   // code-half within tile
    const int shalf   = (w & 1) * 64;    // sample-half

    auto stage = [&](int kt, int b) {
        const char* gH = (const char*)EtHb + (size_t)kt * 16384;
        const char* gL = (const char*)EtLb + (size_t)kt * 16384;
        char* lH = lds + b * 32768;
        char* lL = lH + 16384;
        int off = tid * 16;
        #pragma unroll
        for (int j = 0; j < 4; ++j) {
            __builtin_amdgcn_global_load_lds(
                (const __attribute__((address_space(1))) unsigned int*)(gH + off + j * 4096),
                (__attribute__((address_space(3))) unsigned int*)(lH + off + j * 4096), 16, 0, 0);
            __builtin_amdgcn_global_load_lds(
                (const __attribute__((address_space(1))) unsigned int*)(gL + off + j * 4096),
                (__attribute__((address_space(3))) unsigned int*)(lL + off + j * 4096), 16, 0, 0);
        }
    };

    stage(0, 0);

    // ---- A fragments (x hi/lo) in registers for the whole K sweep: 4 m-groups ----
    short8 ah[4][4], al[4][4];
    #pragma unroll
    for (int m = 0; m < 4; ++m) {
        int samp = n0 + shalf + m * 16 + (lane & 15);
        const float* xp = x + (size_t)samp * DD + ((lane >> 4) * 8);
        #pragma unroll
        for (int t = 0; t < 4; ++t) {
            float4 f0 = *(const float4*)(xp + t * 32);
            float4 f1 = *(const float4*)(xp + t * 32 + 4);
            float fv[8] = {f0.x, f0.y, f0.z, f0.w, f1.x, f1.y, f1.z, f1.w};
            short8 h, l;
            #pragma unroll
            for (int j = 0; j < 8; ++j) {
                unsigned short hh = f2bf(fv[j]);
                h[j] = (short)hh;
                l[j] = (short)f2bf(fv[j] - bf2f(hh));
            }
            ah[m][t] = h;
            al[m][t] = l;
        }
    }
    __syncthreads();

    float b1[4][4], b2[4][4];
    int   kb[4][4];
    #pragma unroll
    for (int m = 0; m < 4; ++m)
        #pragma unroll
        for (int r = 0; r < 4; ++r) { b1[m][r] = 3.4e38f; b2[m][r] = 3.4e38f; kb[m][r] = 0; }

    int buf = 0;
    for (int kt = 0; kt < 64; ++kt) {
        if (kt < 63) stage(kt + 1, buf ^ 1);
        const char* lH = lds + buf * 32768;
        const char* lL = lH + 16384;

        #pragma unroll
        for (int n = 0; n < 2; ++n) {
            int row = rowbase + n * 16 + (lane & 15);
            size_t rbo = (size_t)row << 8;
            unsigned swz = (unsigned)((row & 7) << 4);
            float cn = coln[kt * 64 + row];
            int enc = kt * 2 + n;

            f32x4 acc[4];
            #pragma unroll
            for (int m = 0; m < 4; ++m) acc[m] = (f32x4){0.f, 0.f, 0.f, 0.f};

            __builtin_amdgcn_s_setprio(1);
            #pragma unroll
            for (int t = 0; t < 4; ++t) {
                unsigned coff = ((unsigned)(t * 64 + ((lane >> 4) << 4))) ^ swz;
                short8 bh = *(const short8*)(lH + rbo + coff);
                short8 bl = *(const short8*)(lL + rbo + coff);
                #pragma unroll
                for (int m = 0; m < 4; ++m)
                    acc[m] = __builtin_amdgcn_mfma_f32_16x16x32_bf16(ah[m][t], bh, acc[m], 0, 0, 0);
                #pragma unroll
                for (int m = 0; m < 4; ++m)
                    acc[m] = __builtin_amdgcn_mfma_f32_16x16x32_bf16(al[m][t], bh, acc[m], 0, 0, 0);
                #pragma unroll
                for (int m = 0; m < 4; ++m)
                    acc[m] = __builtin_amdgcn_mfma_f32_16x16x32_bf16(ah[m][t], bl, acc[m], 0, 0, 0);
            }
            __builtin_amdgcn_s_setprio(0);

            #pragma unroll
            for (int m = 0; m < 4; ++m) {
                #pragma unroll
                for (int r = 0; r < 4; ++r) {
                    float d = fmaf(-2.f, acc[m][r], cn);
                    bool lt = d < b1[m][r];
                    b2[m][r] = __builtin_amdgcn_fmed3f(d, b1[m][r], b2[m][r]);
                    b1[m][r] = fminf(b1[m][r], d);
                    kb[m][r] = lt ? enc : kb[m][r];
                }
            }
        }
        __syncthreads();
        buf ^= 1;
    }

    // ---- reduce: cross-lane (16 codes/lane-group), then cross-wave code halves ----
    float* sb1 = (float*)lds;
    int*   si1 = (int*)(lds + 1024);
    float* sb2 = (float*)(lds + 2048);

    #pragma unroll
    for (int m = 0; m < 4; ++m) {
        #pragma unroll
        for (int r = 0; r < 4; ++r) {
            float B1 = b1[m][r];
            int   I1 = (kb[m][r] >> 1) * 64 + rowbase + (kb[m][r] & 1) * 16 + (lane & 15);
            float B2 = b2[m][r];
            #pragma unroll
            for (int msk = 1; msk < 16; msk <<= 1) {
                float ob1 = __shfl_xor(B1, msk);
                int   oi1 = __shfl_xor(I1, msk);
                float ob2 = __shfl_xor(B2, msk);
                mrg(B1, I1, B2, ob1, oi1, ob2);
            }
            if ((lane & 15) == 0) {
                int sl = shalf + m * 16 + ((lane >> 4) << 2) + r;   // 0..127
                int ch = w >> 1;
                sb1[ch * 128 + sl] = B1;
                si1[ch * 128 + sl] = I1;
                sb2[ch * 128 + sl] = B2;
            }
        }
    }
    __syncthreads();
    if (tid < 128) {
        float B1 = sb1[tid]; int I1 = si1[tid]; float B2 = sb2[tid];
        mrg(B1, I1, B2, sb1[128 + tid], si1[128 + tid], sb2[128 + tid]);
        idx_out[n0 + tid] = I1;
        atomicAdd(&counts[I1], 1u);   // provisional count (rescore fixes deltas)
        if (B2 - B1 < MARGIN) {
            int p = atomicAdd(ambCnt, 1);
            ambList[p] = n0 + tid;
        }
    }
}

// ---- exact fp32 rescore, k-CHUNKED: each block = (batch of 16 samples) x
//      (chunk of 512 codes). Per-code fmaf order identical to full-scan. ----
__global__ __launch_bounds__(256) void k_rescore(const float* __restrict__ x,
                                                 const float* __restrict__ E,
                                                 const float* __restrict__ coln,
                                                 const int* __restrict__ ambCnt,
                                                 const int* __restrict__ ambList,
                                                 float* __restrict__ pval,
                                                 int* __restrict__ pidx) {
    __shared__ float xs[RB][DD];
    __shared__ float xn[RB];
    __shared__ float rb1[RB][256];
    __shared__ int   ri1[RB][256];

    const int tid = threadIdx.x;
    const int cnt = *ambCnt;
    const int nbatch = (cnt + RB - 1) / RB;
    const int nwork = nbatch * 8;

    for (int wk = blockIdx.x; wk < nwork; wk += gridDim.x) {
        const int b  = wk >> 3;
        const int ch = wk & 7;
        const int e0 = b * RB;
        const int nb = min(RB, cnt - e0);
        __syncthreads();
        #pragma unroll
        for (int p = 0; p < 2; ++p) {
            int slot = p * 256 + tid;
            int e = slot >> 5, c = slot & 31;
            if (e < nb) {
                int s = ambList[e0 + e];
                *(float4*)&xs[e][c * 4] = *(const float4*)&x[(size_t)s * DD + c * 4];
            } else {
                float4 z; z.x = z.y = z.z = z.w = 0.f;
                *(float4*)&xs[e][c * 4] = z;
            }
        }
        __syncthreads();
        if (tid < RB) {
            float a = 0.f;
            for (int d = 0; d < DD; ++d) a = fmaf(xs[tid][d], xs[tid][d], a);
            xn[tid] = a;
        }
        __syncthreads();

        const int ka  = ch * 512 + tid;      // chunk codes [ch*512, ch*512+512)
        const int kb2 = ka + 256;
        const float* Ea = E + ka;
        const float* Eb = E + kb2;
        float acca[RB], accb[RB];
        #pragma unroll
        for (int e = 0; e < RB; ++e) { acca[e] = 0.f; accb[e] = 0.f; }

        float4 cA, cB, nA, nB;
        {
            cA.x = Ea[0];                  cA.y = Ea[(size_t)1 * NR_EMB];
            cA.z = Ea[(size_t)2 * NR_EMB]; cA.w = Ea[(size_t)3 * NR_EMB];
            cB.x = Eb[0];                  cB.y = Eb[(size_t)1 * NR_EMB];
            cB.z = Eb[(size_t)2 * NR_EMB]; cB.w = Eb[(size_t)3 * NR_EMB];
            const size_t d1 = (size_t)4 * NR_EMB;
            nA.x = Ea[d1];                nA.y = Ea[d1 + NR_EMB];
            nA.z = Ea[d1 + 2 * NR_EMB];   nA.w = Ea[d1 + 3 * NR_EMB];
            nB.x = Eb[d1];                nB.y = Eb[d1 + NR_EMB];
            nB.z = Eb[d1 + 2 * NR_EMB];   nB.w = Eb[d1 + 3 * NR_EMB];
        }

        for (int d4 = 0; d4 < 30; ++d4) {
            float4 fA, fB;
            const size_t dn = (size_t)(d4 * 4 + 8) * NR_EMB;
            fA.x = Ea[dn];                fA.y = Ea[dn + NR_EMB];
            fA.z = Ea[dn + 2 * NR_EMB];   fA.w = Ea[dn + 3 * NR_EMB];
            fB.x = Eb[dn];                fB.y = Eb[dn + NR_EMB];
            fB.z = Eb[dn + 2 * NR_EMB];   fB.w = Eb[dn + 3 * NR_EMB];
            #pragma unroll
            for (int e = 0; e < RB; ++e) {
                float4 xv = *(const float4*)&xs[e][d4 * 4];
                acca[e] = fmaf(xv.x, cA.x, acca[e]);
                acca[e] = fmaf(xv.y, cA.y, acca[e]);
                acca[e] = fmaf(xv.z, cA.z, acca[e]);
                acca[e] = fmaf(xv.w, cA.w, acca[e]);
                accb[e] = fmaf(xv.x, cB.x, accb[e]);
                accb[e] = fmaf(xv.y, cB.y, accb[e]);
                accb[e] = fmaf(xv.z, cB.z, accb[e]);
                accb[e] = fmaf(xv.w, cB.w, accb[e]);
            }
            cA = nA; cB = nB; nA = fA; nB = fB;
        }
        #pragma unroll
        for (int e = 0; e < RB; ++e) {   // d4 = 30 (in cA/cB)
            float4 xv = *(const float4*)&xs[e][120];
            acca[e] = fmaf(xv.x, cA.x, acca[e]);
            acca[e] = fmaf(xv.y, cA.y, acca[e]);
            acca[e] = fmaf(xv.z, cA.z, acca[e]);
            acca[e] = fmaf(xv.w, cA.w, acca[e]);
            accb[e] = fmaf(xv.x, cB.x, accb[e]);
            accb[e] = fmaf(xv.y, cB.y, accb[e]);
            accb[e] = fmaf(xv.z, cB.z, accb[e]);
            accb[e] = fmaf(xv.w, cB.w, accb[e]);
        }
        #pragma unroll
        for (int e = 0; e < RB; ++e) {   // d4 = 31 (in nA/nB)
            float4 xv = *(const float4*)&xs[e][124];
            acca[e] = fmaf(xv.x, nA.x, acca[e]);
            acca[e] = fmaf(xv.y, nA.y, acca[e]);
            acca[e] = fmaf(xv.z, nA.z, acca[e]);
            acca[e] = fmaf(xv.w, nA.w, acca[e]);
            accb[e] = fmaf(xv.x, nB.x, accb[e]);
            accb[e] = fmaf(xv.y, nB.y, accb[e]);
            accb[e] = fmaf(xv.z, nB.z, accb[e]);
            accb[e] = fmaf(xv.w, nB.w, accb[e]);
        }

        const float cna = coln[ka];
        const float cnb = coln[kb2];
        float b1[RB]; int i1[RB];
        #pragma unroll
        for (int e = 0; e < RB; ++e) {
            float da = (xn[e] - 2.0f * acca[e]) + cna;   // numpy association order
            float db = (xn[e] - 2.0f * accb[e]) + cnb;
            bool ltb = db < da;                          // ka < kb2: strict <
            b1[e] = ltb ? db : da;
            i1[e] = ltb ? kb2 : ka;
        }

        #pragma unroll
        for (int e = 0; e < RB; ++e) { rb1[e][tid] = b1[e]; ri1[e][tid] = i1[e]; }
        __syncthreads();
        {
            int g = tid >> 4, l = tid & 15;
            float B = rb1[g][l]; int I = ri1[g][l];
            #pragma unroll
            for (int j = 1; j < 16; ++j) {
                float ob = rb1[g][l + 16 * j]; int oi = ri1[g][l + 16 * j];
                if (ob < B || (ob == B && oi < I)) { B = ob; I = oi; }
            }
            #pragma unroll
            for (int m = 1; m < 16; m <<= 1) {
                float ob = __shfl_xor(B, m, 16);
                int   oi = __shfl_xor(I, m, 16);
                if (ob < B || (ob == B && oi < I)) { B = ob; I = oi; }
            }
            if (l == 0 && g < nb) {
                pval[wk * RB + g] = B;
                pidx[wk * RB + g] = I;
            }
        }
    }
}

// ---- fused: rescore-merge (rfinal) + stats + exclusive prefix. 1 block. ----
__global__ __launch_bounds__(256) void k_rstats(const int* __restrict__ ambCnt,
                                                const int* __restrict__ ambList,
                                                const float* __restrict__ pval,
                                                const int* __restrict__ pidx,
                                                int* __restrict__ idx_out,
                                                unsigned int* __restrict__ counts,
                                                const float* __restrict__ emaC,
                                                float* __restrict__ outC,
                                                float* __restrict__ scal,
                                                float* __restrict__ outPerp,
                                                int* __restrict__ off,
                                                int* __restrict__ cursor) {
    const int tid = threadIdx.x;
    // ---- phase 1: merge 8 chunk-partials per ambiguous sample ----
    const int cnt = *ambCnt;
    for (int i = tid; i < cnt; i += 256) {
        int b = i >> 4, g = i & 15;
        float B = pval[(b * 8) * RB + g];
        int   I = pidx[(b * 8) * RB + g];
        #pragma unroll
        for (int ch = 1; ch < 8; ++ch) {
            float ob = pval[(b * 8 + ch) * RB + g];
            int   oi = pidx[(b * 8 + ch) * RB + g];
            if (ob < B || (ob == B && oi < I)) { B = ob; I = oi; }
        }
        int s = ambList[i];
        int old = idx_out[s];
        if (I != old) {
            atomicSub(&counts[old], 1u);
            atomicAdd(&counts[I], 1u);
            idx_out[s] = I;
        }
    }
    __syncthreads();

    // ---- phase 2: stats + prefix (identical arithmetic to prior rounds) ----
    __shared__ float rs[256], rp[256];
    __shared__ int rc[256];
    float sc = 0.f, sp = 0.f;
    int csum = 0;
    int lc[16];
    #pragma unroll
    for (int j = 0; j < 16; ++j) {
        int k = tid * 16 + j;
        int c = (int)counts[k];
        lc[j] = csum; csum += c;
        float nc = emaC[k] * 0.99f + (float)c * 0.01f;
        outC[k] = nc;
        sc += nc;
        float p = (float)c * (1.0f / 65536.0f);
        sp += p * logf(p + 1e-10f);
    }
    rs[tid] = sc; rp[tid] = sp; rc[tid] = csum;
    __syncthreads();
    for (int o = 1; o < 256; o <<= 1) {
        int v = (tid >= o) ? rc[tid - o] : 0;
        __syncthreads();
        rc[tid] += v;
        __syncthreads();
    }
    const int base = rc[tid] - csum;
    #pragma unroll
    for (int j = 0; j < 16; ++j) {
        int k = tid * 16 + j;
        int o = base + lc[j];
        off[k] = o;
        cursor[k] = o;
    }
    for (int o = 128; o > 0; o >>= 1) {
        if (tid < o) { rs[tid] += rs[tid + o]; rp[tid] += rp[tid + o]; }
        __syncthreads();
    }
    if (tid == 0) {
        scal[0] = rs[0];
        outPerp[0] = expf(-rp[0]);
    }
}

// ---- CSR build: fill buckets ----
__global__ __launch_bounds__(256) void k_fill(const int* __restrict__ idx,
                                              int* __restrict__ cursor,
                                              int* __restrict__ bucket) {
    for (int i = blockIdx.x * 256 + threadIdx.x; i < NTOT; i += gridDim.x * 256) {
        int k = idx[i];
        int p = atomicAdd(&cursor[k], 1);
        bucket[p] = i;
    }
}

// ---- per-code dw sum (atomic-free, coalesced, 2-ahead bucket prefetch) ----
__global__ __launch_bounds__(128) void k_dw(const float* __restrict__ x,
                                            const int* __restrict__ off,
                                            const unsigned int* __restrict__ counts,
                                            const int* __restrict__ bucket,
                                            float* __restrict__ dwT) {
    const int k = blockIdx.x;
    const int d = threadIdx.x;
    const int o = off[k];
    const int c = (int)counts[k];
    float acc = 0.f;
    if (c > 0) {
        int s0 = bucket[o];
        int s1 = (c > 1) ? bucket[o + 1] : 0;
        int p = 0;
        for (; p < c - 2; ++p) {
            int s2 = bucket[o + p + 2];
            acc += x[(size_t)s0 * DD + d];
            s0 = s1; s1 = s2;
        }
        acc += x[(size_t)s0 * DD + d];
        if (c > 1) acc += x[(size_t)s1 * DD + d];
    }
    dwT[(size_t)k * DD + d] = acc;
}

__global__ __launch_bounds__(256) void k_emb(const float* __restrict__ emaDw,
                                             const float* __restrict__ emaC,
                                             const unsigned int* __restrict__ counts,
                                             const float* __restrict__ dwT,
                                             const float* __restrict__ scal,
                                             float* __restrict__ outDw,
                                             float* __restrict__ outEmb,
                                             float* __restrict__ embT) {
    int g = blockIdx.x * 256 + threadIdx.x;
    int d = g >> 12;
    int k = g & 4095;
    float dw  = emaDw[g] * 0.99f + dwT[k * DD + d] * 0.01f;
    float cnt = (float)counts[k];
    float nc  = emaC[k] * 0.99f + cnt * 0.01f;
    float n   = scal[0];
    float denom = n * (nc + 1e-5f) / (n + 0.04096f);
    float e = dw / denom;
    outDw[g]  = dw;
    outEmb[g] = e;
    embT[k * DD + d] = e;
}

// ---- gather + straight-through + loss partials: 8 floats/thread ----
__global__ __launch_bounds__(256) void k_gather(const float* __restrict__ x,
                                                const float* __restrict__ embT,
                                                const int* __restrict__ idx,
                                                float* __restrict__ q,
                                                float* __restrict__ lpart) {
    __shared__ float wred[4];
    int g = blockIdx.x * 256 + threadIdx.x;
    int n = g >> 4;
    int c = g & 15;
    int k = idx[n];
    const float* ep = &embT[(size_t)k * DD + c * 8];
    const float* xp = &x[(size_t)n * DD + c * 8];
    float4 e0 = *(const float4*)(ep);
    float4 e1 = *(const float4*)(ep + 4);
    float4 x0 = *(const float4*)(xp);
    float4 x1 = *(const float4*)(xp + 4);
    float s = 0.f;
    float4 q0, q1;
    {
        float dx = e0.x - x0.x, dy = e0.y - x0.y, dz = e0.z - x0.z, dw = e0.w - x0.w;
        q0.x = x0.x + dx; q0.y = x0.y + dy; q0.z = x0.z + dz; q0.w = x0.w + dw;
        s += dx * dx + dy * dy + dz * dz + dw * dw;
    }
    {
        float dx = e1.x - x1.x, dy = e1.y - x1.y, dz = e1.z - x1.z, dw = e1.w - x1.w;
        q1.x = x1.x + dx; q1.y = x1.y + dy; q1.z = x1.z + dz; q1.w = x1.w + dw;
        s += dx * dx + dy * dy + dz * dz + dw * dw;
    }
    float* qp = &q[(size_t)n * DD + c * 8];
    *(float4*)(qp)     = q0;
    *(float4*)(qp + 4) = q1;
    #pragma unroll
    for (int off = 32; off > 0; off >>= 1) s += __shfl_down(s, off);
    if ((threadIdx.x & 63) == 0) wred[threadIdx.x >> 6] = s;
    __syncthreads();
    if (threadIdx.x == 0)
        lpart[blockIdx.x] = wred[0] + wred[1] + wred[2] + wred[3];
}

__global__ __launch_bounds__(256) void k_final(const float* __restrict__ lpart,
                                               float* __restrict__ outLoss) {
    __shared__ float r[256];
    float s = 0.f;
    for (int i = threadIdx.x; i < 4096; i += 256) s += lpart[i];
    r[threadIdx.x] = s;
    __syncthreads();
    for (int off = 128; off > 0; off >>= 1) {
        if (threadIdx.x < off) r[threadIdx.x] += r[threadIdx.x + off];
        __syncthreads();
    }
    if (threadIdx.x == 0) outLoss[0] = r[0] * (1.0f / 8388608.0f);
}

extern "C" void kernel_launch(void* const* d_in, const int* in_sizes, int n_in,
                              void* d_out, int out_size, void* d_ws, size_t ws_size,
                              hipStream_t stream) {
    const float* x     = (const float*)d_in[0];
    const float* E     = (const float*)d_in[1];
    const float* emaC  = (const float*)d_in[2];
    const float* emaDw = (const float*)d_in[3];
    float* out = (float*)d_out;
    char*  ws  = (char*)d_ws;

    unsigned int*   cnts  = (unsigned int*)(ws + WS_CNT);
    float*          scal  = (float*)(ws + WS_SCAL);
    int*            ambC  = (int*)(ws + WS_AMBC);
    float*          coln  = (float*)(ws + WS_COLN);
    int*            idx   = (int*)(ws + WS_IDX);
    float*          embT  = (float*)(ws + WS_EMBT);   // pidx partials early / embT late
    float*          lpart = (float*)(ws + WS_LPART);
    unsigned short* EtHb  = (unsigned short*)(ws + WS_ETH);
    unsigned short* EtLb  = (unsigned short*)(ws + WS_ETL);
    int*            ambL  = (int*)(ws + WS_AMBL);
    int*            off   = (int*)(ws + WS_OFF);
    int*            cur   = (int*)(ws + WS_CUR);
    int*            bkt   = (int*)(ws + WS_BKT);
    float*          dwT   = (float*)(ws + WS_DWT);    // pval partials early / dwT late

    float* pval = dwT;            // aliased: dwT written later by k_dw
    int*   pidx = (int*)embT;     // aliased: embT written later by k_emb

    k_prep_e<<<128, 128, 0, stream>>>(E, EtHb, EtLb, coln, cnts, ambC, scal);
    k_dist<<<NTOT / 128, 256, 0, stream>>>(x, EtHb, EtLb, coln, idx, cnts, ambC, ambL);
    k_rescore<<<2048, 256, 0, stream>>>(x, E, coln, ambC, ambL, pval, pidx);
    k_rstats<<<1, 256, 0, stream>>>(ambC, ambL, pval, pidx, idx, cnts,
                                    emaC, out + OUT_CLUS, scal, out + OUT_PERP, off, cur);
    k_fill<<<256, 256, 0, stream>>>(idx, cur, bkt);
    k_dw<<<NR_EMB, 128, 0, stream>>>(x, off, cnts, bkt, dwT);
    k_emb<<<(DD * NR_EMB) / 256, 256, 0, stream>>>(emaDw, emaC, cnts, dwT, scal,
                                                   out + OUT_DW, out + OUT_EMB, embT);
    k_gather<<<(NTOT * DD / 8) / 256, 256, 0, stream>>>(x, embT, idx, out + OUT_Q, lpart);
    k_final<<<1, 256, 0, stream>>>(lpart, out + OUT_LOSS);
}